// Round 1
// baseline (319.336 us; speedup 1.0000x reference)
//
#include <hip/hip_runtime.h>

#define LL  210      // window length
#define MM  55       // channels
#define NBM 440      // B*M
#define DM  256      // d_model
#define MLT 11550    // MM*LL
#define BLM 92400    // B*LL*MM (one output slab)

__device__ __forceinline__ float wave_sum(float v) {
#pragma unroll
    for (int off = 32; off > 0; off >>= 1) v += __shfl_xor(v, off, 64);
    return v;
}

// ---------- norm (RevIN, two-pass) + fused transpose of num-branch W1 ----------
__global__ __launch_bounds__(256) void knorm_trans(
        const float* __restrict__ x,
        const float* __restrict__ nw0, const float* __restrict__ nw1,
        const float* __restrict__ nw2,
        float* __restrict__ xt, float* __restrict__ w1t) {
    __shared__ float red[4];
    const int t = threadIdx.x;
    if (blockIdx.x < NBM) {
        const int bm = blockIdx.x, b = bm / MM, m = bm % MM;
        const int wid = t >> 6, lane = t & 63;
        float v = (t < LL) ? x[b * MLT + t * MM + m] : 0.f;
        float sv = wave_sum(v);
        if (lane == 0) red[wid] = sv;
        __syncthreads();
        float mean = (red[0] + red[1] + red[2] + red[3]) * (1.f / 210.f);
        __syncthreads();
        float dv = (t < LL) ? v - mean : 0.f;
        float sq = wave_sum(dv * dv);
        if (lane == 0) red[wid] = sq;
        __syncthreads();
        float var = (red[0] + red[1] + red[2] + red[3]) * (1.f / 210.f);
        float inv = rsqrtf(var + 1e-5f);
        if (t < LL) xt[bm * LL + t] = dv * inv;
    } else {
        // transpose the three num-branch W1 (256 x ind) -> (ind x 256) into ws
        int e = (int)(blockIdx.x - NBM) * 256 + t;   // [0, 139*256)
        const float* src; int ind, off, rel;
        if (e < 69 * DM)       { src = nw0; ind = 69; off = 0;        rel = e; }
        else if (e < 110 * DM) { src = nw1; ind = 41; off = 69 * DM;  rel = e - 69 * DM; }
        else                   { src = nw2; ind = 29; off = 110 * DM; rel = e - 110 * DM; }
        int d = rel / ind, k = rel - d * ind;
        w1t[off + k * DM + d] = src[d * ind + k];
    }
}

// ---------- size branches: one thread per output position ----------
template <int IND>
__device__ __forceinline__ void size_body(const float* __restrict__ xs,
                                          const float* __restrict__ w1s,
                                          const float* __restrict__ b1s,
                                          const float* __restrict__ w2s,
                                          float b2v, int n, int j, int bm,
                                          float* __restrict__ out) {
    const int t = threadIdx.x;
    if (t >= LL) return;
    const int l = t, i = l / n, k = l - i * n;
    float f[IND];
#pragma unroll
    for (int idx = 0; idx < IND; ++idx) {
        int row = idx < i ? idx : idx + 1;       // leave-one-out over p rows
        f[idx] = xs[row * n + k];
    }
    float y = b2v;
    for (int d = 0; d < DM; ++d) {
        float acc = b1s[d];
#pragma unroll
        for (int idx = 0; idx < IND; ++idx) acc += w1s[d * IND + idx] * f[idx];
        y += fmaxf(acc, 0.f) * w2s[d];
    }
    const int b = bm / MM, m = bm - b * MM;
    out[j * BLM + b * MLT + l * MM + m] = y;
}

__global__ __launch_bounds__(256) void ksize(const float* __restrict__ xt,
        const float* __restrict__ W1_0, const float* __restrict__ b1_0, const float* __restrict__ W2_0, const float* __restrict__ b2_0,
        const float* __restrict__ W1_1, const float* __restrict__ b1_1, const float* __restrict__ W2_1, const float* __restrict__ b2_1,
        const float* __restrict__ W1_2, const float* __restrict__ b1_2, const float* __restrict__ W2_2, const float* __restrict__ b2_2,
        float* __restrict__ out) {
    const int blk = blockIdx.x;
    const int j = blk / NBM, bm = blk - j * NBM;
    const int p = (j == 0) ? 3 : ((j == 1) ? 5 : 7);
    const int n = LL / p, ind = p - 1;
    const float* W1 = (j == 0) ? W1_0 : ((j == 1) ? W1_1 : W1_2);
    const float* b1 = (j == 0) ? b1_0 : ((j == 1) ? b1_1 : b1_2);
    const float* W2 = (j == 0) ? W2_0 : ((j == 1) ? W2_1 : W2_2);
    const float* b2 = (j == 0) ? b2_0 : ((j == 1) ? b2_1 : b2_2);
    __shared__ float xs[LL];
    __shared__ float w1s[DM * 6];
    __shared__ float b1s[DM];
    __shared__ float w2s[DM];
    const int t = threadIdx.x;
    if (t < LL) xs[t] = xt[bm * LL + t];
    b1s[t] = b1[t];
    w2s[t] = W2[t];
    for (int e = t; e < DM * ind; e += 256) w1s[e] = W1[e];
    __syncthreads();
    const float b2v = b2[0];
    if (ind == 2)      size_body<2>(xs, w1s, b1s, w2s, b2v, n, j, bm, out);
    else if (ind == 4) size_body<4>(xs, w1s, b1s, w2s, b2v, n, j, bm, out);
    else               size_body<6>(xs, w1s, b1s, w2s, b2v, n, j, bm, out);
}

// ---------- num branches: prefix/suffix leave-one-out trick ----------
// block = one (bm, r) row, 4 waves split the k range; lane owns dims lane*4..lane*4+3
__global__ __launch_bounds__(256) void knum(const float* __restrict__ xt, const float* __restrict__ w1t,
        const float* __restrict__ b1_0, const float* __restrict__ W2_0, const float* __restrict__ b2_0,
        const float* __restrict__ b1_1, const float* __restrict__ W2_1, const float* __restrict__ b2_1,
        const float* __restrict__ b1_2, const float* __restrict__ W2_2, const float* __restrict__ b2_2,
        float* __restrict__ out) {
    const int blk = blockIdx.x;
    int j, p, rel;
    const float *b1, *W2, *b2, *wt;
    if (blk < 1320)      { j = 0; p = 3; rel = blk;        wt = w1t;            b1 = b1_0; W2 = W2_0; b2 = b2_0; }
    else if (blk < 3520) { j = 1; p = 5; rel = blk - 1320; wt = w1t + 69 * DM;  b1 = b1_1; W2 = W2_1; b2 = b2_1; }
    else                 { j = 2; p = 7; rel = blk - 3520; wt = w1t + 110 * DM; b1 = b1_2; W2 = W2_2; b2 = b2_2; }
    const int n = LL / p;
    const int bm = rel / p, r = rel - bm * p;
    const int t = threadIdx.x, wid = t >> 6, lane = t & 63;
    const float* xrow = xt + bm * LL + r * n;
    const float4 b1v = *(const float4*)&b1[lane * 4];
    const float4 w2v = *(const float4*)&W2[lane * 4];
    const float b2v = b2[0];
    const int s = (wid * n) >> 2, e = ((wid + 1) * n) >> 2;
    // A[s] = sum_{q<s} W1[:,q] x[q] ; B[s] = sum_{q>s} W1[:,q-1] x[q]
    float ax = 0.f, ay = 0.f, az = 0.f, aw = 0.f;
    float bx = 0.f, by = 0.f, bz = 0.f, bw = 0.f;
    for (int q = 0; q < s; ++q) {
        float xv = xrow[q];
        const float4 w = *(const float4*)&wt[q * DM + lane * 4];
        ax += w.x * xv; ay += w.y * xv; az += w.z * xv; aw += w.w * xv;
    }
    for (int q = s + 1; q < n; ++q) {
        float xv = xrow[q];
        const float4 w = *(const float4*)&wt[(q - 1) * DM + lane * 4];
        bx += w.x * xv; by += w.y * xv; bz += w.z * xv; bw += w.w * xv;
    }
    for (int k = s; k < e; ++k) {
        float hx = fmaxf(ax + bx + b1v.x, 0.f);
        float hy = fmaxf(ay + by + b1v.y, 0.f);
        float hz = fmaxf(az + bz + b1v.z, 0.f);
        float hw = fmaxf(aw + bw + b1v.w, 0.f);
        float part = hx * w2v.x + hy * w2v.y + hz * w2v.z + hw * w2v.w;
        part = wave_sum(part);
        if (lane == 0) {
            // scrambled reshape: flat f = (k*p + r)*440 + bm -> (b,m,l); write (b,l,m)
            int fi = (k * p + r) * NBM + bm;
            int ob = fi / MLT; int rem = fi - ob * MLT;
            int om = rem / LL; int ol = rem - om * LL;
            out[(3 + j) * BLM + ob * MLT + ol * MM + om] = part + b2v;
        }
        if (k + 1 < e) {
            const float4 w = *(const float4*)&wt[k * DM + lane * 4];
            float xk = xrow[k], xk1 = xrow[k + 1];
            ax += w.x * xk;  ay += w.y * xk;  az += w.z * xk;  aw += w.w * xk;
            bx -= w.x * xk1; by -= w.y * xk1; bz -= w.z * xk1; bw -= w.w * xk1;
        }
    }
}

// ---------- seq branches (size_seq: isNum=0, num_seq: isNum=1) ----------
__global__ __launch_bounds__(256) void kseq(const float* __restrict__ xt,
        const float* __restrict__ W1a, const float* __restrict__ b1a, const float* __restrict__ W2a, const float* __restrict__ b2a,
        const float* __restrict__ W1b, const float* __restrict__ b1b, const float* __restrict__ W2b, const float* __restrict__ b2b,
        const int isNum, float* __restrict__ out) {
    const int blk = blockIdx.x;
    const int jj = blk / NBM, bm = blk - jj * NBM;
    const int p = jj ? 7 : 5;
    const int n = LL / (p * 6);              // 7 or 5
    const int nrows = isNum ? (n - 1) : (p - 1);
    const int ind = nrows * 6;
    const float* W1 = jj ? W1b : W1a;
    const float* b1 = jj ? b1b : b1a;
    const float* W2 = jj ? W2b : W2a;
    const float* b2 = jj ? b2b : b2a;
    __shared__ float xs[LL];
    __shared__ alignas(16) float w1t[36 * DM];
    __shared__ alignas(16) float b1s[DM];
    __shared__ alignas(16) float w2s[6 * DM];
    __shared__ float b2s[6];
    const int t = threadIdx.x;
    if (t < LL) xs[t] = xt[bm * LL + t];
    b1s[t] = b1[t];
    for (int e = t; e < 6 * DM; e += 256) w2s[e] = W2[e];
    if (t < 6) b2s[t] = b2[t];
    for (int e = t; e < DM * ind; e += 256) { int d = e / ind, fi = e - d * ind; w1t[fi * DM + d] = W1[e]; }
    __syncthreads();
    const int wid = t >> 6, lane = t & 63;
    const float4 b1v = *(const float4*)&b1s[lane * 4];
    const int b = bm / MM, m = bm - b * MM;
    for (int q = wid; q < 35; q += 4) {
        int a0, k0;
        if (isNum) { k0 = q / p; a0 = q - k0 * p; }   // q = k*p + r : leave out col k0, fixed row a0=r
        else       { a0 = q / n; k0 = q - a0 * n; }   // q = i*n + k : leave out row a0=i, fixed col k0
        const int pivot = isNum ? k0 : a0;
        float accx = b1v.x, accy = b1v.y, accz = b1v.z, accw = b1v.w;
        for (int idx = 0; idx < nrows; ++idx) {
            int row = idx < pivot ? idx : idx + 1;
            int xbase = isNum ? (a0 * n + row) * 6 : (row * n + k0) * 6;
#pragma unroll
            for (int tt = 0; tt < 6; ++tt) {
                float fv = xs[xbase + tt];
                const float4 w = *(const float4*)&w1t[(idx * 6 + tt) * DM + lane * 4];
                accx += w.x * fv; accy += w.y * fv; accz += w.z * fv; accw += w.w * fv;
            }
        }
        accx = fmaxf(accx, 0.f); accy = fmaxf(accy, 0.f);
        accz = fmaxf(accz, 0.f); accw = fmaxf(accw, 0.f);
        float po[6];
#pragma unroll
        for (int tt = 0; tt < 6; ++tt) {
            const float4 w2v = *(const float4*)&w2s[tt * DM + lane * 4];
            float pp = accx * w2v.x + accy * w2v.y + accz * w2v.z + accw * w2v.w;
            po[tt] = wave_sum(pp);
        }
        if (lane == 0) {
            if (isNum) {
                int c2 = q / 5, dd = q - c2 * 5;      // d0 = patch_seq[0] = 5 hardcoded in reference
#pragma unroll
                for (int tt = 0; tt < 6; ++tt) {
                    int l = dd * 42 + c2 * 6 + tt;
                    out[(8 + jj) * BLM + b * MLT + l * MM + m] = po[tt] + b2s[tt];
                }
            } else {
#pragma unroll
                for (int tt = 0; tt < 6; ++tt) {
                    int l = q * 6 + tt;
                    out[(6 + jj) * BLM + b * MLT + l * MM + m] = po[tt] + b2s[tt];
                }
            }
        }
    }
}

extern "C" void kernel_launch(void* const* d_in, const int* in_sizes, int n_in,
                              void* d_out, int out_size, void* d_ws, size_t ws_size,
                              hipStream_t stream) {
    (void)in_sizes; (void)n_in; (void)out_size; (void)ws_size;
    const float* x = (const float*)d_in[0];
    const float *s1W[3], *s1b[3], *s2W[3], *s2b[3], *n1W[3], *n1b[3], *n2W[3], *n2b[3];
    for (int j = 0; j < 3; ++j) {
        int base = 1 + j * 8;
        s1W[j] = (const float*)d_in[base + 0]; s1b[j] = (const float*)d_in[base + 1];
        s2W[j] = (const float*)d_in[base + 2]; s2b[j] = (const float*)d_in[base + 3];
        n1W[j] = (const float*)d_in[base + 4]; n1b[j] = (const float*)d_in[base + 5];
        n2W[j] = (const float*)d_in[base + 6]; n2b[j] = (const float*)d_in[base + 7];
    }
    const float *ss1W[2], *ss1b[2], *ss2W[2], *ss2b[2], *ns1W[2], *ns1b[2], *ns2W[2], *ns2b[2];
    for (int j = 0; j < 2; ++j) {
        int base = 25 + j * 8;
        ss1W[j] = (const float*)d_in[base + 0]; ss1b[j] = (const float*)d_in[base + 1];
        ss2W[j] = (const float*)d_in[base + 2]; ss2b[j] = (const float*)d_in[base + 3];
        ns1W[j] = (const float*)d_in[base + 4]; ns1b[j] = (const float*)d_in[base + 5];
        ns2W[j] = (const float*)d_in[base + 6]; ns2b[j] = (const float*)d_in[base + 7];
    }
    float* out = (float*)d_out;
    float* xt  = (float*)d_ws;            // 440*210 floats
    float* w1t = xt + NBM * LL;           // (69+41+29)*256 floats (transposed num W1s)

    knorm_trans<<<579, 256, 0, stream>>>(x, n1W[0], n1W[1], n1W[2], xt, w1t);
    ksize<<<1320, 256, 0, stream>>>(xt,
        s1W[0], s1b[0], s2W[0], s2b[0],
        s1W[1], s1b[1], s2W[1], s2b[1],
        s1W[2], s1b[2], s2W[2], s2b[2], out);
    knum<<<6600, 256, 0, stream>>>(xt, w1t,
        n1b[0], n2W[0], n2b[0],
        n1b[1], n2W[1], n2b[1],
        n1b[2], n2W[2], n2b[2], out);
    kseq<<<880, 256, 0, stream>>>(xt,
        ss1W[0], ss1b[0], ss2W[0], ss2b[0],
        ss1W[1], ss1b[1], ss2W[1], ss2b[1], 0, out);
    kseq<<<880, 256, 0, stream>>>(xt,
        ns1W[0], ns1b[0], ns2W[0], ns2b[0],
        ns1W[1], ns1b[1], ns2W[1], ns2b[1], 1, out);
}

// Round 2
// 260.594 us; speedup vs baseline: 1.2254x; 1.2254x over previous
//
#include <hip/hip_runtime.h>

#define LL  210      // window length
#define MM  55       // channels
#define NBM 440      // B*M
#define DM  256      // d_model
#define MLT 11550    // MM*LL
#define BLM 92400    // B*LL*MM (one output slab)

__device__ __forceinline__ float wave_sum(float v) {
#pragma unroll
    for (int off = 32; off > 0; off >>= 1) v += __shfl_xor(v, off, 64);
    return v;
}

__device__ __forceinline__ void fma4(float4& a, const float4 w, const float s) {
    a.x += w.x * s; a.y += w.y * s; a.z += w.z * s; a.w += w.w * s;
}
__device__ __forceinline__ void fms4(float4& a, const float4 w, const float s) {
    a.x -= w.x * s; a.y -= w.y * s; a.z -= w.z * s; a.w -= w.w * s;
}

// ---------- norm (RevIN, two-pass) + fused transpose of num-branch W1 ----------
__global__ __launch_bounds__(256) void knorm_trans(
        const float* __restrict__ x,
        const float* __restrict__ nw0, const float* __restrict__ nw1,
        const float* __restrict__ nw2,
        float* __restrict__ xt, float* __restrict__ w1t) {
    __shared__ float red[4];
    const int t = threadIdx.x;
    if (blockIdx.x < NBM) {
        const int bm = blockIdx.x, b = bm / MM, m = bm % MM;
        const int wid = t >> 6, lane = t & 63;
        float v = (t < LL) ? x[b * MLT + t * MM + m] : 0.f;
        float sv = wave_sum(v);
        if (lane == 0) red[wid] = sv;
        __syncthreads();
        float mean = (red[0] + red[1] + red[2] + red[3]) * (1.f / 210.f);
        __syncthreads();
        float dv = (t < LL) ? v - mean : 0.f;
        float sq = wave_sum(dv * dv);
        if (lane == 0) red[wid] = sq;
        __syncthreads();
        float var = (red[0] + red[1] + red[2] + red[3]) * (1.f / 210.f);
        float inv = rsqrtf(var + 1e-5f);
        if (t < LL) xt[bm * LL + t] = dv * inv;
    } else {
        // transpose the three num-branch W1 (256 x ind) -> (ind x 256) into ws
        int e = (int)(blockIdx.x - NBM) * 256 + t;   // [0, 139*256)
        const float* src; int ind, off, rel;
        if (e < 69 * DM)       { src = nw0; ind = 69; off = 0;        rel = e; }
        else if (e < 110 * DM) { src = nw1; ind = 41; off = 69 * DM;  rel = e - 69 * DM; }
        else                   { src = nw2; ind = 29; off = 110 * DM; rel = e - 110 * DM; }
        int d = rel / ind, k = rel - d * ind;
        w1t[off + k * DM + d] = src[d * ind + k];
    }
}

// ---------- size branches: one thread per output position, packed weights ----------
template <int IND>
__device__ __forceinline__ void ksize_body(const float* __restrict__ xt,
        const float* __restrict__ W1, const float* __restrict__ b1,
        const float* __restrict__ W2, const float* __restrict__ b2,
        int bm, int j, float* __restrict__ smem, float* __restrict__ out) {
    constexpr int P = IND + 1;
    constexpr int N = LL / P;
    constexpr int WPAD = (IND == 2) ? 2 : ((IND == 4) ? 4 : 8);
    float* w1p = smem;              // DM*WPAD (padded, vector-readable)
    float* bw  = smem + DM * 8;     // DM*2 interleaved (b1, w2)
    float* xs  = smem + DM * 10;    // LL
    const int t = threadIdx.x;
    if (t < LL) xs[t] = xt[bm * LL + t];
    bw[2 * t]     = b1[t];
    bw[2 * t + 1] = W2[t];
    for (int e = t; e < DM * WPAD; e += 256) {
        int d = e / WPAD, c = e - d * WPAD;
        w1p[e] = (c < IND) ? W1[d * IND + c] : 0.f;
    }
    __syncthreads();
    if (t >= LL) return;
    const int l = t, i = l / N, k = l - i * N;
    float f[IND];
#pragma unroll
    for (int idx = 0; idx < IND; ++idx) {
        int row = idx < i ? idx : idx + 1;       // leave-one-out over p rows
        f[idx] = xs[row * N + k];
    }
    float y = b2[0];
#pragma unroll 4
    for (int d = 0; d < DM; ++d) {
        const float2 bwv = *(const float2*)&bw[2 * d];
        float acc = bwv.x;
        if constexpr (WPAD == 2) {
            const float2 w = *(const float2*)&w1p[d * 2];
            acc += w.x * f[0] + w.y * f[1];
        } else if constexpr (WPAD == 4) {
            const float4 w = *(const float4*)&w1p[d * 4];
            acc += w.x * f[0] + w.y * f[1] + w.z * f[2] + w.w * f[3];
        } else {
            const float4 wa = *(const float4*)&w1p[d * 8];
            const float4 wb = *(const float4*)&w1p[d * 8 + 4];
            acc += wa.x * f[0] + wa.y * f[1] + wa.z * f[2] + wa.w * f[3]
                 + wb.x * f[4] + wb.y * f[5];
        }
        y += fmaxf(acc, 0.f) * bwv.y;
    }
    const int b = bm / MM, m = bm - b * MM;
    out[j * BLM + b * MLT + l * MM + m] = y;
}

__global__ __launch_bounds__(256) void ksize_all(const float* __restrict__ xt,
        const float* __restrict__ W1_0, const float* __restrict__ b1_0, const float* __restrict__ W2_0, const float* __restrict__ b2_0,
        const float* __restrict__ W1_1, const float* __restrict__ b1_1, const float* __restrict__ W2_1, const float* __restrict__ b2_1,
        const float* __restrict__ W1_2, const float* __restrict__ b1_2, const float* __restrict__ W2_2, const float* __restrict__ b2_2,
        float* __restrict__ out) {
    __shared__ __align__(16) float smem[DM * 10 + LL];
    const int blk = blockIdx.x;
    if (blk < NBM)           ksize_body<2>(xt, W1_0, b1_0, W2_0, b2_0, blk,           0, smem, out);
    else if (blk < 2 * NBM)  ksize_body<4>(xt, W1_1, b1_1, W2_1, b2_1, blk - NBM,     1, smem, out);
    else                     ksize_body<6>(xt, W1_2, b1_2, W2_2, b2_2, blk - 2 * NBM, 2, smem, out);
}

// ---------- num branches: prefix/suffix trick, wave = 2 series over full k ----------
template <int P, int N>
__device__ __forceinline__ void knum_body(const float* __restrict__ xt,
        const float* __restrict__ wt, const float* __restrict__ b1,
        const float* __restrict__ W2, const float* __restrict__ b2,
        int r, int bm0, int j, float* __restrict__ xl, float* __restrict__ out) {
    const int t = threadIdx.x;
    for (int e = t; e < 8 * N; e += 256) {              // xl[q][g] transposed stage
        int g = e / N, q = e - g * N;
        xl[q * 8 + g] = xt[(bm0 + g) * LL + r * N + q];
    }
    if (t < 8) xl[N * 8 + t] = 0.f;                      // zero pad row for k+1 read
    __syncthreads();
    const int wid = t >> 6, lane = t & 63;
    const int g0 = wid * 2;
    const float4 b1v = *(const float4*)&b1[lane * 4];
    const float4 w2v = *(const float4*)&W2[lane * 4];
    const float b2v = b2[0];
    float4 A0 = b1v, A1 = b1v;                           // b1 folded into A
    float4 B0 = make_float4(0.f, 0.f, 0.f, 0.f), B1 = B0;
#pragma unroll 4
    for (int q = 1; q < N; ++q) {                        // suffix build
        const float4 w = *(const float4*)&wt[(q - 1) * DM + lane * 4];
        const float2 xv = *(const float2*)&xl[q * 8 + g0];
        fma4(B0, w, xv.x); fma4(B1, w, xv.y);
    }
    // per-lane output addresses for k = lane, k = lane + 64 (scrambled reshape)
    int adr[2][2];
#pragma unroll
    for (int s2 = 0; s2 < 2; ++s2) {
        int kk = lane + 64 * s2; int kc = kk < N ? kk : 0;
#pragma unroll
        for (int g = 0; g < 2; ++g) {
            int fi = (kc * P + r) * NBM + (bm0 + g0 + g);
            int ob = fi / MLT, rem = fi - ob * MLT;
            int om = rem / LL, ol = rem - om * LL;
            adr[s2][g] = (3 + j) * BLM + ob * MLT + ol * MM + om;
        }
    }
    float yA0 = 0.f, yA1 = 0.f, yB0 = 0.f, yB1 = 0.f;
#pragma unroll 2
    for (int k = 0; k < N; ++k) {
        const float4 w = *(const float4*)&wt[k * DM + lane * 4];
        const float2 xk  = *(const float2*)&xl[k * 8 + g0];
        const float2 xk1 = *(const float2*)&xl[(k + 1) * 8 + g0];
        float hx = fmaxf(A0.x + B0.x, 0.f), hy = fmaxf(A0.y + B0.y, 0.f);
        float hz = fmaxf(A0.z + B0.z, 0.f), hw = fmaxf(A0.w + B0.w, 0.f);
        float y0 = hx * w2v.x + hy * w2v.y + hz * w2v.z + hw * w2v.w;
        hx = fmaxf(A1.x + B1.x, 0.f); hy = fmaxf(A1.y + B1.y, 0.f);
        hz = fmaxf(A1.z + B1.z, 0.f); hw = fmaxf(A1.w + B1.w, 0.f);
        float y1 = hx * w2v.x + hy * w2v.y + hz * w2v.z + hw * w2v.w;
        y0 = wave_sum(y0); y1 = wave_sum(y1);
        if (k == lane)      { yA0 = y0; yA1 = y1; }
        if (k == lane + 64) { yB0 = y0; yB1 = y1; }
        fma4(A0, w, xk.x);  fma4(A1, w, xk.y);
        fms4(B0, w, xk1.x); fms4(B1, w, xk1.y);
    }
    if (lane < N)      { out[adr[0][0]] = yA0 + b2v; out[adr[0][1]] = yA1 + b2v; }
    if (lane + 64 < N) { out[adr[1][0]] = yB0 + b2v; out[adr[1][1]] = yB1 + b2v; }
}

__global__ __launch_bounds__(256) void knum_all(const float* __restrict__ xt,
        const float* __restrict__ w1t,
        const float* __restrict__ b1_0, const float* __restrict__ W2_0, const float* __restrict__ b2_0,
        const float* __restrict__ b1_1, const float* __restrict__ W2_1, const float* __restrict__ b2_1,
        const float* __restrict__ b1_2, const float* __restrict__ W2_2, const float* __restrict__ b2_2,
        float* __restrict__ out) {
    __shared__ __align__(16) float xl[71 * 8];
    const int blk = blockIdx.x;
    if (blk < 165) {
        int rel = blk;       int bm0 = (rel / 3) * 8, r = rel % 3;
        knum_body<3, 70>(xt, w1t,            b1_0, W2_0, b2_0, r, bm0, 0, xl, out);
    } else if (blk < 440) {
        int rel = blk - 165; int bm0 = (rel / 5) * 8, r = rel % 5;
        knum_body<5, 42>(xt, w1t + 69 * DM,  b1_1, W2_1, b2_1, r, bm0, 1, xl, out);
    } else {
        int rel = blk - 440; int bm0 = (rel / 7) * 8, r = rel % 7;
        knum_body<7, 30>(xt, w1t + 110 * DM, b1_2, W2_2, b2_2, r, bm0, 2, xl, out);
    }
}

// ---------- seq branches fused (size_seq + num_seq), 2 series per block ----------
template <int ISNUM, int P, int N>
__device__ __forceinline__ void kseq_body(const float* __restrict__ xt,
        const float* __restrict__ W1, const float* __restrict__ b1,
        const float* __restrict__ W2, const float* __restrict__ b2,
        int bm0, int slab, float* __restrict__ smem, float* __restrict__ out) {
    constexpr int NROWS = ISNUM ? (N - 1) : (P - 1);
    constexpr int IND = NROWS * 6;
    constexpr int WST = DM + 8;                 // padded row stride (bank + align)
    float* w1s  = smem;                         // IND * WST (transposed)
    float* w2s  = smem + 36 * WST;              // 6*DM
    float* b1s  = w2s + 6 * DM;                 // DM
    float* b2s_ = b1s + DM;                     // 8
    float* xl   = b2s_ + 8;                     // LL*2 interleaved by g
    const int t = threadIdx.x;
    for (int e = t; e < DM * IND; e += 256) {
        int d = e / IND, fi = e - d * IND;
        w1s[fi * WST + d] = W1[e];
    }
    for (int e = t; e < 6 * DM; e += 256) w2s[e] = W2[e];
    b1s[t] = b1[t];
    if (t < 6) b2s_[t] = b2[t];
    for (int e = t; e < 2 * LL; e += 256) {
        int g = e / LL, q = e - g * LL;
        xl[q * 2 + g] = xt[(bm0 + g) * LL + q];
    }
    __syncthreads();
    const int wid = t >> 6, lane = t & 63;
    const float4 b1v = *(const float4*)&b1s[lane * 4];
    for (int q = wid; q < 35; q += 4) {
        int a0, k0;
        if (ISNUM) { k0 = q / P; a0 = q - k0 * P; }     // q = k*p + r
        else       { a0 = q / N; k0 = q - a0 * N; }     // q = i*n + k
        const int pivot = ISNUM ? k0 : a0;
        float4 acc0 = b1v, acc1 = b1v;
#pragma unroll 2
        for (int idx = 0; idx < NROWS; ++idx) {
            int row = idx < pivot ? idx : idx + 1;
            int xbase = ISNUM ? (a0 * N + row) * 6 : (row * N + k0) * 6;
#pragma unroll
            for (int tt = 0; tt < 6; ++tt) {
                const float2 xv = *(const float2*)&xl[(xbase + tt) * 2];
                const float4 w = *(const float4*)&w1s[(idx * 6 + tt) * WST + lane * 4];
                fma4(acc0, w, xv.x); fma4(acc1, w, xv.y);
            }
        }
        acc0.x = fmaxf(acc0.x, 0.f); acc0.y = fmaxf(acc0.y, 0.f);
        acc0.z = fmaxf(acc0.z, 0.f); acc0.w = fmaxf(acc0.w, 0.f);
        acc1.x = fmaxf(acc1.x, 0.f); acc1.y = fmaxf(acc1.y, 0.f);
        acc1.z = fmaxf(acc1.z, 0.f); acc1.w = fmaxf(acc1.w, 0.f);
        float po0[6], po1[6];
#pragma unroll
        for (int tt = 0; tt < 6; ++tt) {
            const float4 w2v = *(const float4*)&w2s[tt * DM + lane * 4];
            float p0 = acc0.x * w2v.x + acc0.y * w2v.y + acc0.z * w2v.z + acc0.w * w2v.w;
            float p1 = acc1.x * w2v.x + acc1.y * w2v.y + acc1.z * w2v.z + acc1.w * w2v.w;
            po0[tt] = wave_sum(p0);
            po1[tt] = wave_sum(p1);
        }
        if (lane < 2) {
            const int bm = bm0 + lane;
            const int b = bm / MM, m = bm - b * MM;
            const int c2 = q / 5, dd = q - c2 * 5;      // d0 = patch_seq[0] = 5 (ref hardcode)
#pragma unroll
            for (int tt = 0; tt < 6; ++tt) {
                int l = ISNUM ? (dd * 42 + c2 * 6 + tt) : (q * 6 + tt);
                out[slab + b * MLT + l * MM + m] = (lane ? po1[tt] : po0[tt]) + b2s_[tt];
            }
        }
    }
}

__global__ __launch_bounds__(256) void kseq_all(const float* __restrict__ xt,
        const float* __restrict__ ss1W0, const float* __restrict__ ss1b0, const float* __restrict__ ss2W0, const float* __restrict__ ss2b0,
        const float* __restrict__ ss1W1, const float* __restrict__ ss1b1, const float* __restrict__ ss2W1, const float* __restrict__ ss2b1,
        const float* __restrict__ ns1W0, const float* __restrict__ ns1b0, const float* __restrict__ ns2W0, const float* __restrict__ ns2b0,
        const float* __restrict__ ns1W1, const float* __restrict__ ns1b1, const float* __restrict__ ns2W1, const float* __restrict__ ns2b1,
        float* __restrict__ out) {
    __shared__ __align__(16) float smem[36 * (DM + 8) + 6 * DM + DM + 8 + 2 * LL];
    const int blk = blockIdx.x;
    const int tc = blk / 220, bm0 = (blk - tc * 220) * 2;
    if (tc == 0)      kseq_body<0, 5, 7>(xt, ss1W0, ss1b0, ss2W0, ss2b0, bm0, 6 * BLM, smem, out);
    else if (tc == 1) kseq_body<0, 7, 5>(xt, ss1W1, ss1b1, ss2W1, ss2b1, bm0, 7 * BLM, smem, out);
    else if (tc == 2) kseq_body<1, 5, 7>(xt, ns1W0, ns1b0, ns2W0, ns2b0, bm0, 8 * BLM, smem, out);
    else              kseq_body<1, 7, 5>(xt, ns1W1, ns1b1, ns2W1, ns2b1, bm0, 9 * BLM, smem, out);
}

extern "C" void kernel_launch(void* const* d_in, const int* in_sizes, int n_in,
                              void* d_out, int out_size, void* d_ws, size_t ws_size,
                              hipStream_t stream) {
    (void)in_sizes; (void)n_in; (void)out_size; (void)ws_size;
    const float* x = (const float*)d_in[0];
    const float *s1W[3], *s1b[3], *s2W[3], *s2b[3], *n1W[3], *n1b[3], *n2W[3], *n2b[3];
    for (int j = 0; j < 3; ++j) {
        int base = 1 + j * 8;
        s1W[j] = (const float*)d_in[base + 0]; s1b[j] = (const float*)d_in[base + 1];
        s2W[j] = (const float*)d_in[base + 2]; s2b[j] = (const float*)d_in[base + 3];
        n1W[j] = (const float*)d_in[base + 4]; n1b[j] = (const float*)d_in[base + 5];
        n2W[j] = (const float*)d_in[base + 6]; n2b[j] = (const float*)d_in[base + 7];
    }
    const float *ss1W[2], *ss1b[2], *ss2W[2], *ss2b[2], *ns1W[2], *ns1b[2], *ns2W[2], *ns2b[2];
    for (int j = 0; j < 2; ++j) {
        int base = 25 + j * 8;
        ss1W[j] = (const float*)d_in[base + 0]; ss1b[j] = (const float*)d_in[base + 1];
        ss2W[j] = (const float*)d_in[base + 2]; ss2b[j] = (const float*)d_in[base + 3];
        ns1W[j] = (const float*)d_in[base + 4]; ns1b[j] = (const float*)d_in[base + 5];
        ns2W[j] = (const float*)d_in[base + 6]; ns2b[j] = (const float*)d_in[base + 7];
    }
    float* out = (float*)d_out;
    float* xt  = (float*)d_ws;            // 440*210 floats
    float* w1t = xt + NBM * LL;           // (69+41+29)*256 floats (transposed num W1s)

    knorm_trans<<<579, 256, 0, stream>>>(x, n1W[0], n1W[1], n1W[2], xt, w1t);
    ksize_all<<<1320, 256, 0, stream>>>(xt,
        s1W[0], s1b[0], s2W[0], s2b[0],
        s1W[1], s1b[1], s2W[1], s2b[1],
        s1W[2], s1b[2], s2W[2], s2b[2], out);
    knum_all<<<825, 256, 0, stream>>>(xt, w1t,
        n1b[0], n2W[0], n2b[0],
        n1b[1], n2W[1], n2b[1],
        n1b[2], n2W[2], n2b[2], out);
    kseq_all<<<880, 256, 0, stream>>>(xt,
        ss1W[0], ss1b[0], ss2W[0], ss2b[0],
        ss1W[1], ss1b[1], ss2W[1], ss2b[1],
        ns1W[0], ns1b[0], ns2W[0], ns2b[0],
        ns1W[1], ns1b[1], ns2W[1], ns2b[1], out);
}

// Round 3
// 246.632 us; speedup vs baseline: 1.2948x; 1.0566x over previous
//
#include <hip/hip_runtime.h>

#define LL  210      // window length
#define MM  55       // channels
#define NBM 440      // B*M
#define DM  256      // d_model
#define MLT 11550    // MM*LL
#define BLM 92400    // B*LL*MM (one output slab)

// ws layout (floats):
#define XTG_OFF  0        // 55 grps * 210 pos * 8 series = 92400
#define W1T_OFF  92400    // 259 transposed cols * 256 = 66304
#define REC_OFF  158704   // ksize packed records = 5120
// w1t column offsets: num0=0(69), num1=69(41), num2=110(29),
//                     ss0=139(24), ss1=163(36), ns0=199(36), ns1=235(24)

__device__ __forceinline__ float wave_sum(float v) {
#pragma unroll
    for (int off = 32; off > 0; off >>= 1) v += __shfl_xor(v, off, 64);
    return v;
}

__device__ __forceinline__ void fma4(float4& a, const float4 w, const float s) {
    a.x += w.x * s; a.y += w.y * s; a.z += w.z * s; a.w += w.w * s;
}
__device__ __forceinline__ void fms4(float4& a, const float4 w, const float s) {
    a.x -= w.x * s; a.y -= w.y * s; a.z -= w.z * s; a.w -= w.w * s;
}

// 8 simultaneous 64-lane reductions: returns sum over all lanes of y[lane&7]
__device__ __forceinline__ float bfly8(const float y[8], const int lane) {
    float z[4];
#pragma unroll
    for (int i = 0; i < 4; ++i) {
        float snd = (lane & 1) ? y[2*i] : y[2*i+1];
        float rcv = __shfl_xor(snd, 1, 64);
        z[i] = ((lane & 1) ? y[2*i+1] : y[2*i]) + rcv;
    }
    float u[2];
#pragma unroll
    for (int i = 0; i < 2; ++i) {
        float snd = (lane & 2) ? z[2*i] : z[2*i+1];
        float rcv = __shfl_xor(snd, 2, 64);
        u[i] = ((lane & 2) ? z[2*i+1] : z[2*i]) + rcv;
    }
    {
        float snd = (lane & 4) ? u[0] : u[1];
        float rcv = __shfl_xor(snd, 4, 64);
        float w = ((lane & 4) ? u[1] : u[0]) + rcv;
        w += __shfl_xor(w, 8, 64);
        w += __shfl_xor(w, 16, 64);
        w += __shfl_xor(w, 32, 64);
        return w;
    }
}

// ---------- norm (RevIN) -> xtg; transpose all branch W1s; pack ksize records ----------
__global__ __launch_bounds__(256) void knorm_trans(
        const float* __restrict__ x,
        const float* __restrict__ nw0, const float* __restrict__ nw1, const float* __restrict__ nw2,
        const float* __restrict__ ssw0, const float* __restrict__ ssw1,
        const float* __restrict__ nsw0, const float* __restrict__ nsw1,
        const float* __restrict__ s1W0, const float* __restrict__ s1b0, const float* __restrict__ s2W0,
        const float* __restrict__ s1W1, const float* __restrict__ s1b1, const float* __restrict__ s2W1,
        const float* __restrict__ s1W2, const float* __restrict__ s1b2, const float* __restrict__ s2W2,
        float* __restrict__ xtg, float* __restrict__ w1t, float* __restrict__ recs) {
    __shared__ float red[4];
    const int t = threadIdx.x;
    const int blk = blockIdx.x;
    if (blk < NBM) {
        const int bm = blk, b = bm / MM, m = bm % MM;
        const int wid = t >> 6, lane = t & 63;
        float v = (t < LL) ? x[b * MLT + t * MM + m] : 0.f;
        float sv = wave_sum(v);
        if (lane == 0) red[wid] = sv;
        __syncthreads();
        float mean = (red[0] + red[1] + red[2] + red[3]) * (1.f / 210.f);
        __syncthreads();
        float dv = (t < LL) ? v - mean : 0.f;
        float sq = wave_sum(dv * dv);
        if (lane == 0) red[wid] = sq;
        __syncthreads();
        float var = (red[0] + red[1] + red[2] + red[3]) * (1.f / 210.f);
        float inv = rsqrtf(var + 1e-5f);
        if (t < LL) xtg[(bm >> 3) * 1680 + t * 8 + (bm & 7)] = dv * inv;
    } else if (blk < NBM + 259) {
        const int e = (blk - NBM) * 256 + t;   // [0, 259*256)
        const int cg = e >> 8, d = e & 255;
        const float* src; int ind, c;
        if (cg < 69)       { src = nw0;  ind = 69; c = cg; }
        else if (cg < 110) { src = nw1;  ind = 41; c = cg - 69; }
        else if (cg < 139) { src = nw2;  ind = 29; c = cg - 110; }
        else if (cg < 163) { src = ssw0; ind = 24; c = cg - 139; }
        else if (cg < 199) { src = ssw1; ind = 36; c = cg - 163; }
        else if (cg < 235) { src = nsw0; ind = 36; c = cg - 199; }
        else               { src = nsw1; ind = 24; c = cg - 235; }
        w1t[cg * DM + d] = src[d * ind + c];
    } else {
        const int e = (blk - NBM - 259) * 256 + t;   // [0, 5120)
        float v;
        if (e < 1024) {
            int d = e >> 2, c = e & 3;
            v = (c < 2) ? s1W0[d * 2 + c] : (c == 2 ? s1b0[d] : s2W0[d]);
        } else if (e < 3072) {
            int rel = e - 1024, d = rel >> 3, c = rel & 7;
            v = (c < 4) ? s1W1[d * 4 + c] : (c == 4 ? s1b1[d] : (c == 5 ? s2W1[d] : 0.f));
        } else {
            int rel = e - 3072, d = rel >> 3, c = rel & 7;
            v = (c < 6) ? s1W2[d * 6 + c] : (c == 6 ? s1b2[d] : s2W2[d]);
        }
        recs[e] = v;
    }
}

// ---------- size branches: thread-per-output, scalar-load packed records, zero LDS ----------
template <int IND>
__device__ __forceinline__ void ksize_body(const float* __restrict__ xtg,
        const float* __restrict__ rec, const float* __restrict__ b2,
        int bm, int j, float* __restrict__ out) {
    constexpr int N = LL / (IND + 1);
    const int t = threadIdx.x;
    if (t >= LL) return;
    const float* xs = xtg + (bm >> 3) * 1680 + (bm & 7);
    const int i = t / N, k = t - i * N;
    float f[IND];
#pragma unroll
    for (int idx = 0; idx < IND; ++idx) {
        int row = idx + (idx >= i);
        f[idx] = xs[(row * N + k) * 8];
    }
    float y = b2[0];
    const float4* r4 = (const float4*)rec;
    if constexpr (IND == 2) {
#pragma unroll 8
        for (int d = 0; d < DM; ++d) {
            const float4 rv = r4[d];
            y += fmaxf(rv.x * f[0] + rv.y * f[1] + rv.z, 0.f) * rv.w;
        }
    } else if constexpr (IND == 4) {
#pragma unroll 4
        for (int d = 0; d < DM; ++d) {
            const float4 a = r4[2 * d], b = r4[2 * d + 1];
            y += fmaxf(a.x*f[0] + a.y*f[1] + a.z*f[2] + a.w*f[3] + b.x, 0.f) * b.y;
        }
    } else {
#pragma unroll 4
        for (int d = 0; d < DM; ++d) {
            const float4 a = r4[2 * d], b = r4[2 * d + 1];
            y += fmaxf(a.x*f[0] + a.y*f[1] + a.z*f[2] + a.w*f[3] + b.x*f[4] + b.y*f[5] + b.z, 0.f) * b.w;
        }
    }
    const int b_ = bm / MM, m = bm - b_ * MM;
    out[j * BLM + b_ * MLT + t * MM + m] = y;
}

__global__ __launch_bounds__(256) void ksize_all(const float* __restrict__ xtg,
        const float* __restrict__ recs,
        const float* __restrict__ b2_0, const float* __restrict__ b2_1, const float* __restrict__ b2_2,
        float* __restrict__ out) {
    const int blk = blockIdx.x;
    if (blk < NBM)          ksize_body<2>(xtg, recs,        b2_0, blk,           0, out);
    else if (blk < 2 * NBM) ksize_body<4>(xtg, recs + 1024, b2_1, blk - NBM,     1, out);
    else                    ksize_body<6>(xtg, recs + 3072, b2_2, blk - 2 * NBM, 2, out);
}

// ---------- num branches: prefix/suffix trick, chunked butterfly reduce, zero LDS ----------
template <int P, int N>
__device__ __forceinline__ void knum_body(const float* __restrict__ xtg,
        const float* __restrict__ wt, const float* __restrict__ b1,
        const float* __restrict__ W2, const float* __restrict__ b2,
        int grp, int r, int j, float* __restrict__ out) {
    const int t = threadIdx.x, wid = t >> 6, lane = t & 63;
    const int g0 = wid * 2;
    const float* xb = xtg + grp * 1680 + r * N * 8 + g0;   // uniform float2 at +q*8
    const float4 b1v = *(const float4*)&b1[lane * 4];
    const float4 w2v = *(const float4*)&W2[lane * 4];
    const float b2v = b2[0];
    const float* wl = wt + lane * 4;
    float4 A0 = b1v, A1 = b1v;
    float4 B0 = make_float4(0.f,0.f,0.f,0.f), B1 = B0;
#pragma unroll 2
    for (int q = 1; q < N; ++q) {                           // suffix build
        const float4 w = *(const float4*)(wl + (q - 1) * DM);
        const float2 xv = *(const float2*)(xb + q * 8);
        fma4(B0, w, xv.x); fma4(B1, w, xv.y);
    }
    constexpr int NFULL = N / 8, TAIL = N - NFULL * 8;      // N%8 != 0 for all branches
    for (int c = 0; c <= NFULL; ++c) {
        float y0[8], y1[8];
        const bool full = (c < NFULL);
#pragma unroll
        for (int i = 0; i < 8; ++i) {
            const int k = c * 8 + i;
            if (full || i < TAIL) {
                float hx = fmaxf(A0.x + B0.x, 0.f), hy = fmaxf(A0.y + B0.y, 0.f);
                float hz = fmaxf(A0.z + B0.z, 0.f), hw = fmaxf(A0.w + B0.w, 0.f);
                y0[i] = hx * w2v.x + hy * w2v.y + hz * w2v.z + hw * w2v.w;
                hx = fmaxf(A1.x + B1.x, 0.f); hy = fmaxf(A1.y + B1.y, 0.f);
                hz = fmaxf(A1.z + B1.z, 0.f); hw = fmaxf(A1.w + B1.w, 0.f);
                y1[i] = hx * w2v.x + hy * w2v.y + hz * w2v.z + hw * w2v.w;
                if (full || i < TAIL - 1) {                 // update (k+1 < N)
                    const float4 w = *(const float4*)(wl + k * DM);
                    const float2 xk  = *(const float2*)(xb + k * 8);
                    const float2 xk1 = *(const float2*)(xb + k * 8 + 8);
                    fma4(A0, w, xk.x);  fma4(A1, w, xk.y);
                    fms4(B0, w, xk1.x); fms4(B1, w, xk1.y);
                }
            } else { y0[i] = 0.f; y1[i] = 0.f; }
        }
        const float v0 = bfly8(y0, lane), v1 = bfly8(y1, lane);
        if (lane < 16) {
            const int k = c * 8 + (lane & 7);
            if (k < N) {
                const int bm = grp * 8 + g0 + (lane >> 3);
                const float val = ((lane < 8) ? v0 : v1) + b2v;
                const int fi = (k * P + r) * NBM + bm;
                const int ob = fi / MLT, rem = fi - ob * MLT;
                const int om = rem / LL, ol = rem - om * LL;
                out[(3 + j) * BLM + ob * MLT + ol * MM + om] = val;
            }
        }
    }
}

__global__ __launch_bounds__(256) void knum_all(const float* __restrict__ xtg,
        const float* __restrict__ w1t,
        const float* __restrict__ b1_0, const float* __restrict__ W2_0, const float* __restrict__ b2_0,
        const float* __restrict__ b1_1, const float* __restrict__ W2_1, const float* __restrict__ b2_1,
        const float* __restrict__ b1_2, const float* __restrict__ W2_2, const float* __restrict__ b2_2,
        float* __restrict__ out) {
    const int blk = blockIdx.x;
    if (blk < 165) {
        int rel = blk;       knum_body<3, 70>(xtg, w1t,            b1_0, W2_0, b2_0, rel / 3, rel % 3, 0, out);
    } else if (blk < 440) {
        int rel = blk - 165; knum_body<5, 42>(xtg, w1t + 69 * DM,  b1_1, W2_1, b2_1, rel / 5, rel % 5, 1, out);
    } else {
        int rel = blk - 440; knum_body<7, 30>(xtg, w1t + 110 * DM, b1_2, W2_2, b2_2, rel / 7, rel % 7, 2, out);
    }
}

// ---------- seq branches: G=8 series/block, scalar x-loads, butterfly epilogue, zero LDS ----------
template <int ISNUM, int P, int N>
__device__ __forceinline__ void kseq_body(const float* __restrict__ xtg,
        const float* __restrict__ w1tb, const float* __restrict__ b1,
        const float* __restrict__ W2, const float* __restrict__ b2,
        int grp, int slab, float* __restrict__ out) {
    constexpr int NROWS = ISNUM ? (N - 1) : (P - 1);
    const int t = threadIdx.x, wid = t >> 6, lane = t & 63;
    const float4 b1v = *(const float4*)&b1[lane * 4];
    const float* xg = xtg + grp * 1680;
    float b2r[6];
#pragma unroll
    for (int tt = 0; tt < 6; ++tt) b2r[tt] = b2[tt];
    const int bm = grp * 8 + (lane & 7);
    const int b_ = bm / MM, m = bm - b_ * MM;
    for (int q = wid; q < 35; q += 4) {
        int pivot, fix;
        if (ISNUM) { pivot = q / P; fix = q - pivot * P; }   // LOO over n cols, fixed row r
        else       { pivot = q / N; fix = q - pivot * N; }   // LOO over p rows, fixed col k
        float4 acc[8];
#pragma unroll
        for (int g = 0; g < 8; ++g) acc[g] = b1v;
        const float* wl = w1tb + lane * 4;
        for (int idx = 0; idx < NROWS; ++idx) {
            const int row = idx + (idx >= pivot);
            const int pos0 = ISNUM ? (fix * N + row) * 6 : (row * N + fix) * 6;
            const float* xp = xg + pos0 * 8;
#pragma unroll
            for (int tt = 0; tt < 6; ++tt) {
                const float4 xa = *(const float4*)(xp + tt * 8);
                const float4 xc = *(const float4*)(xp + tt * 8 + 4);
                const float4 w  = *(const float4*)wl; wl += DM;
                fma4(acc[0], w, xa.x); fma4(acc[1], w, xa.y);
                fma4(acc[2], w, xa.z); fma4(acc[3], w, xa.w);
                fma4(acc[4], w, xc.x); fma4(acc[5], w, xc.y);
                fma4(acc[6], w, xc.z); fma4(acc[7], w, xc.w);
            }
        }
#pragma unroll
        for (int g = 0; g < 8; ++g) {
            acc[g].x = fmaxf(acc[g].x, 0.f); acc[g].y = fmaxf(acc[g].y, 0.f);
            acc[g].z = fmaxf(acc[g].z, 0.f); acc[g].w = fmaxf(acc[g].w, 0.f);
        }
        const int c2 = q / 5, dd = q - c2 * 5;   // d0 = patch_seq[0] = 5 (ref hardcode)
#pragma unroll
        for (int h = 0; h < 2; ++h) {
            float yv0[8], yv1[8], yv2[8];
#pragma unroll
            for (int tt2 = 0; tt2 < 3; ++tt2) {
                const int tt = h * 3 + tt2;
                const float4 w2v = *(const float4*)&W2[tt * DM + lane * 4];
                float* yv = (tt2 == 0) ? yv0 : ((tt2 == 1) ? yv1 : yv2);
#pragma unroll
                for (int g = 0; g < 8; ++g)
                    yv[g] = acc[g].x * w2v.x + acc[g].y * w2v.y + acc[g].z * w2v.z + acc[g].w * w2v.w;
            }
            const float r0 = bfly8(yv0, lane);
            const float r1 = bfly8(yv1, lane);
            const float r2 = bfly8(yv2, lane);
            if (lane < 8) {
#pragma unroll
                for (int tt2 = 0; tt2 < 3; ++tt2) {
                    const int tt = h * 3 + tt2;
                    const int l = ISNUM ? (dd * 42 + c2 * 6 + tt) : (q * 6 + tt);
                    const float rv = (tt2 == 0) ? r0 : ((tt2 == 1) ? r1 : r2);
                    out[slab + b_ * MLT + l * MM + m] = rv + b2r[tt];
                }
            }
        }
    }
}

__global__ __launch_bounds__(256) void kseq_all(const float* __restrict__ xtg,
        const float* __restrict__ w1t,
        const float* __restrict__ ss1b0, const float* __restrict__ ss2W0, const float* __restrict__ ss2b0,
        const float* __restrict__ ss1b1, const float* __restrict__ ss2W1, const float* __restrict__ ss2b1,
        const float* __restrict__ ns1b0, const float* __restrict__ ns2W0, const float* __restrict__ ns2b0,
        const float* __restrict__ ns1b1, const float* __restrict__ ns2W1, const float* __restrict__ ns2b1,
        float* __restrict__ out) {
    const int blk = blockIdx.x;
    const int tc = blk / 55, grp = blk - tc * 55;
    if (tc == 0)      kseq_body<0, 5, 7>(xtg, w1t + 139 * DM, ss1b0, ss2W0, ss2b0, grp, 6 * BLM, out);
    else if (tc == 1) kseq_body<0, 7, 5>(xtg, w1t + 163 * DM, ss1b1, ss2W1, ss2b1, grp, 7 * BLM, out);
    else if (tc == 2) kseq_body<1, 5, 7>(xtg, w1t + 199 * DM, ns1b0, ns2W0, ns2b0, grp, 8 * BLM, out);
    else              kseq_body<1, 7, 5>(xtg, w1t + 235 * DM, ns1b1, ns2W1, ns2b1, grp, 9 * BLM, out);
}

extern "C" void kernel_launch(void* const* d_in, const int* in_sizes, int n_in,
                              void* d_out, int out_size, void* d_ws, size_t ws_size,
                              hipStream_t stream) {
    (void)in_sizes; (void)n_in; (void)out_size; (void)ws_size;
    const float* x = (const float*)d_in[0];
    const float *s1W[3], *s1b[3], *s2W[3], *s2b[3], *n1W[3], *n1b[3], *n2W[3], *n2b[3];
    for (int j = 0; j < 3; ++j) {
        int base = 1 + j * 8;
        s1W[j] = (const float*)d_in[base + 0]; s1b[j] = (const float*)d_in[base + 1];
        s2W[j] = (const float*)d_in[base + 2]; s2b[j] = (const float*)d_in[base + 3];
        n1W[j] = (const float*)d_in[base + 4]; n1b[j] = (const float*)d_in[base + 5];
        n2W[j] = (const float*)d_in[base + 6]; n2b[j] = (const float*)d_in[base + 7];
    }
    const float *ss1W[2], *ss1b[2], *ss2W[2], *ss2b[2], *ns1W[2], *ns1b[2], *ns2W[2], *ns2b[2];
    for (int j = 0; j < 2; ++j) {
        int base = 25 + j * 8;
        ss1W[j] = (const float*)d_in[base + 0]; ss1b[j] = (const float*)d_in[base + 1];
        ss2W[j] = (const float*)d_in[base + 2]; ss2b[j] = (const float*)d_in[base + 3];
        ns1W[j] = (const float*)d_in[base + 4]; ns1b[j] = (const float*)d_in[base + 5];
        ns2W[j] = (const float*)d_in[base + 6]; ns2b[j] = (const float*)d_in[base + 7];
    }
    float* out  = (float*)d_out;
    float* xtg  = (float*)d_ws + XTG_OFF;
    float* w1t  = (float*)d_ws + W1T_OFF;
    float* recs = (float*)d_ws + REC_OFF;

    knorm_trans<<<719, 256, 0, stream>>>(x,
        n1W[0], n1W[1], n1W[2],
        ss1W[0], ss1W[1], ns1W[0], ns1W[1],
        s1W[0], s1b[0], s2W[0],
        s1W[1], s1b[1], s2W[1],
        s1W[2], s1b[2], s2W[2],
        xtg, w1t, recs);
    ksize_all<<<1320, 256, 0, stream>>>(xtg, recs, s2b[0], s2b[1], s2b[2], out);
    knum_all<<<825, 256, 0, stream>>>(xtg, w1t,
        n1b[0], n2W[0], n2b[0],
        n1b[1], n2W[1], n2b[1],
        n1b[2], n2W[2], n2b[2], out);
    kseq_all<<<220, 256, 0, stream>>>(xtg, w1t,
        ss1b[0], ss2W[0], ss2b[0],
        ss1b[1], ss2W[1], ss2b[1],
        ns1b[0], ns2W[0], ns2b[0],
        ns1b[1], ns2W[1], ns2b[1], out);
}

// Round 4
// 222.851 us; speedup vs baseline: 1.4330x; 1.1067x over previous
//
#include <hip/hip_runtime.h>

#define LL  210      // window length
#define MM  55       // channels
#define NBM 440      // B*M
#define DM  256      // d_model
#define MLT 11550    // MM*LL
#define BLM 92400    // B*LL*MM (one output slab)

// ws layout (floats):
#define XTG_OFF  0        // 55 grps * 210 pos * 8 series = 92400
#define W1T_OFF  92400    // 259 transposed cols * 256 = 66304
#define REC_OFF  158704   // ksize packed records = 5120
// w1t column offsets: num0=0(69), num1=69(41), num2=110(29),
//                     ss0=139(24), ss1=163(36), ns0=199(36), ns1=235(24)

__device__ __forceinline__ float wave_sum(float v) {
#pragma unroll
    for (int off = 32; off > 0; off >>= 1) v += __shfl_xor(v, off, 64);
    return v;
}

__device__ __forceinline__ void fma4(float4& a, const float4 w, const float s) {
    a.x += w.x * s; a.y += w.y * s; a.z += w.z * s; a.w += w.w * s;
}
__device__ __forceinline__ void fms4(float4& a, const float4 w, const float s) {
    a.x -= w.x * s; a.y -= w.y * s; a.z -= w.z * s; a.w -= w.w * s;
}

// 8 simultaneous 64-lane reductions: returns sum over all lanes of y[lane&7]
__device__ __forceinline__ float bfly8(const float y[8], const int lane) {
    float z[4];
#pragma unroll
    for (int i = 0; i < 4; ++i) {
        float snd = (lane & 1) ? y[2*i] : y[2*i+1];
        float rcv = __shfl_xor(snd, 1, 64);
        z[i] = ((lane & 1) ? y[2*i+1] : y[2*i]) + rcv;
    }
    float u[2];
#pragma unroll
    for (int i = 0; i < 2; ++i) {
        float snd = (lane & 2) ? z[2*i] : z[2*i+1];
        float rcv = __shfl_xor(snd, 2, 64);
        u[i] = ((lane & 2) ? z[2*i+1] : z[2*i]) + rcv;
    }
    {
        float snd = (lane & 4) ? u[0] : u[1];
        float rcv = __shfl_xor(snd, 4, 64);
        float w = ((lane & 4) ? u[1] : u[0]) + rcv;
        w += __shfl_xor(w, 8, 64);
        w += __shfl_xor(w, 16, 64);
        w += __shfl_xor(w, 32, 64);
        return w;
    }
}

// ---------- prep: RevIN (one-pass stats) -> xtg; transpose W1s; pack ksize records ----------
__global__ __launch_bounds__(256) void knorm_trans(
        const float* __restrict__ x,
        const float* __restrict__ nw0, const float* __restrict__ nw1, const float* __restrict__ nw2,
        const float* __restrict__ ssw0, const float* __restrict__ ssw1,
        const float* __restrict__ nsw0, const float* __restrict__ nsw1,
        const float* __restrict__ s1W0, const float* __restrict__ s1b0, const float* __restrict__ s2W0,
        const float* __restrict__ s1W1, const float* __restrict__ s1b1, const float* __restrict__ s2W1,
        const float* __restrict__ s1W2, const float* __restrict__ s1b2, const float* __restrict__ s2W2,
        float* __restrict__ xtg, float* __restrict__ w1t, float* __restrict__ recs) {
    __shared__ float red[8];
    const int t = threadIdx.x;
    const int blk = blockIdx.x;
    if (blk < NBM) {
        const int bm = blk, b = bm / MM, m = bm % MM;
        const int wid = t >> 6, lane = t & 63;
        float v = (t < LL) ? x[b * MLT + t * MM + m] : 0.f;
        float s1 = wave_sum(v);
        float s2 = wave_sum(v * v);
        if (lane == 0) { red[wid] = s1; red[4 + wid] = s2; }
        __syncthreads();
        float mean = (red[0] + red[1] + red[2] + red[3]) * (1.f / 210.f);
        float msq  = (red[4] + red[5] + red[6] + red[7]) * (1.f / 210.f);
        float var = msq - mean * mean;
        float inv = rsqrtf(var + 1e-5f);
        if (t < LL) xtg[(bm >> 3) * 1680 + t * 8 + (bm & 7)] = (v - mean) * inv;
    } else if (blk < NBM + 259) {
        const int e = (blk - NBM) * 256 + t;   // [0, 259*256)
        const int cg = e >> 8, d = e & 255;
        const float* src; int ind, c;
        if (cg < 69)       { src = nw0;  ind = 69; c = cg; }
        else if (cg < 110) { src = nw1;  ind = 41; c = cg - 69; }
        else if (cg < 139) { src = nw2;  ind = 29; c = cg - 110; }
        else if (cg < 163) { src = ssw0; ind = 24; c = cg - 139; }
        else if (cg < 199) { src = ssw1; ind = 36; c = cg - 163; }
        else if (cg < 235) { src = nsw0; ind = 36; c = cg - 199; }
        else               { src = nsw1; ind = 24; c = cg - 235; }
        w1t[cg * DM + d] = src[d * ind + c];
    } else {
        const int e = (blk - NBM - 259) * 256 + t;   // [0, 5120)
        float v;
        if (e < 1024) {
            int d = e >> 2, c = e & 3;
            v = (c < 2) ? s1W0[d * 2 + c] : (c == 2 ? s1b0[d] : s2W0[d]);
        } else if (e < 3072) {
            int rel = e - 1024, d = rel >> 3, c = rel & 7;
            v = (c < 4) ? s1W1[d * 4 + c] : (c == 4 ? s1b1[d] : (c == 5 ? s2W1[d] : 0.f));
        } else {
            int rel = e - 3072, d = rel >> 3, c = rel & 7;
            v = (c < 6) ? s1W2[d * 6 + c] : (c == 6 ? s1b2[d] : s2W2[d]);
        }
        recs[e] = v;
    }
}

// ---------- size branches: thread-per-output, scalar-load packed records ----------
template <int IND>
__device__ __forceinline__ void ksize_body(const float* __restrict__ xtg,
        const float* __restrict__ rec, const float* __restrict__ b2,
        int bm, int j, float* __restrict__ out) {
    constexpr int N = LL / (IND + 1);
    const int t = threadIdx.x;
    if (t >= LL) return;
    const float* xs = xtg + (bm >> 3) * 1680 + (bm & 7);
    const int i = t / N, k = t - i * N;
    float f[IND];
#pragma unroll
    for (int idx = 0; idx < IND; ++idx) {
        int row = idx + (idx >= i);
        f[idx] = xs[(row * N + k) * 8];
    }
    float y0 = b2[0], y1 = 0.f;
    const float4* r4 = (const float4*)rec;
    if constexpr (IND == 2) {
#pragma unroll 8
        for (int d = 0; d < DM; d += 2) {
            const float4 a = r4[d], b = r4[d + 1];
            y0 += fmaxf(a.x * f[0] + a.y * f[1] + a.z, 0.f) * a.w;
            y1 += fmaxf(b.x * f[0] + b.y * f[1] + b.z, 0.f) * b.w;
        }
    } else if constexpr (IND == 4) {
#pragma unroll 8
        for (int d = 0; d < DM; d += 2) {
            const float4 a = r4[2*d], b = r4[2*d+1];
            const float4 c = r4[2*d+2], e = r4[2*d+3];
            y0 += fmaxf(a.x*f[0] + a.y*f[1] + a.z*f[2] + a.w*f[3] + b.x, 0.f) * b.y;
            y1 += fmaxf(c.x*f[0] + c.y*f[1] + c.z*f[2] + c.w*f[3] + e.x, 0.f) * e.y;
        }
    } else {
#pragma unroll 8
        for (int d = 0; d < DM; d += 2) {
            const float4 a = r4[2*d], b = r4[2*d+1];
            const float4 c = r4[2*d+2], e = r4[2*d+3];
            y0 += fmaxf(a.x*f[0] + a.y*f[1] + a.z*f[2] + a.w*f[3] + b.x*f[4] + b.y*f[5] + b.z, 0.f) * b.w;
            y1 += fmaxf(c.x*f[0] + c.y*f[1] + c.z*f[2] + c.w*f[3] + e.x*f[4] + e.y*f[5] + e.z, 0.f) * e.w;
        }
    }
    const int b_ = bm / MM, m = bm - b_ * MM;
    out[j * BLM + b_ * MLT + t * MM + m] = y0 + y1;
}

// ---------- num branches: prefix/suffix trick, chunked butterfly reduce ----------
template <int P, int N>
__device__ __forceinline__ void knum_body(const float* __restrict__ xtg,
        const float* __restrict__ wt, const float* __restrict__ b1,
        const float* __restrict__ W2, const float* __restrict__ b2,
        int grp, int r, int j, float* __restrict__ out) {
    const int t = threadIdx.x, wid = t >> 6, lane = t & 63;
    const int g0 = wid * 2;
    const float* xb = xtg + grp * 1680 + r * N * 8 + g0;   // uniform float2 at +q*8
    const float4 b1v = *(const float4*)&b1[lane * 4];
    const float4 w2v = *(const float4*)&W2[lane * 4];
    const float b2v = b2[0];
    const float* wl = wt + lane * 4;
    float4 A0 = b1v, A1 = b1v;
    float4 B0 = make_float4(0.f,0.f,0.f,0.f), B1 = B0;
#pragma unroll 2
    for (int q = 1; q < N; ++q) {                           // suffix build
        const float4 w = *(const float4*)(wl + (q - 1) * DM);
        const float2 xv = *(const float2*)(xb + q * 8);
        fma4(B0, w, xv.x); fma4(B1, w, xv.y);
    }
    constexpr int NFULL = N / 8, TAIL = N - NFULL * 8;      // N%8 != 0 for all branches
    for (int c = 0; c <= NFULL; ++c) {
        float y0[8], y1[8];
        const bool full = (c < NFULL);
#pragma unroll
        for (int i = 0; i < 8; ++i) {
            const int k = c * 8 + i;
            if (full || i < TAIL) {
                float hx = fmaxf(A0.x + B0.x, 0.f), hy = fmaxf(A0.y + B0.y, 0.f);
                float hz = fmaxf(A0.z + B0.z, 0.f), hw = fmaxf(A0.w + B0.w, 0.f);
                y0[i] = hx * w2v.x + hy * w2v.y + hz * w2v.z + hw * w2v.w;
                hx = fmaxf(A1.x + B1.x, 0.f); hy = fmaxf(A1.y + B1.y, 0.f);
                hz = fmaxf(A1.z + B1.z, 0.f); hw = fmaxf(A1.w + B1.w, 0.f);
                y1[i] = hx * w2v.x + hy * w2v.y + hz * w2v.z + hw * w2v.w;
                if (full || i < TAIL - 1) {                 // update (k+1 < N)
                    const float4 w = *(const float4*)(wl + k * DM);
                    const float2 xk  = *(const float2*)(xb + k * 8);
                    const float2 xk1 = *(const float2*)(xb + k * 8 + 8);
                    fma4(A0, w, xk.x);  fma4(A1, w, xk.y);
                    fms4(B0, w, xk1.x); fms4(B1, w, xk1.y);
                }
            } else { y0[i] = 0.f; y1[i] = 0.f; }
        }
        const float v0 = bfly8(y0, lane), v1 = bfly8(y1, lane);
        if (lane < 16) {
            const int k = c * 8 + (lane & 7);
            if (k < N) {
                const int bm = grp * 8 + g0 + (lane >> 3);
                const float val = ((lane < 8) ? v0 : v1) + b2v;
                const int fi = (k * P + r) * NBM + bm;
                const int ob = fi / MLT, rem = fi - ob * MLT;
                const int om = rem / LL, ol = rem - om * LL;
                out[(3 + j) * BLM + ob * MLT + ol * MM + om] = val;
            }
        }
    }
}

// ---------- seq branches: G=8 series/block, q-chunked, butterfly epilogue ----------
template <int ISNUM, int P, int N>
__device__ __forceinline__ void kseq_body(const float* __restrict__ xtg,
        const float* __restrict__ w1tb, const float* __restrict__ b1,
        const float* __restrict__ W2, const float* __restrict__ b2,
        int grp, int qc, int slab, float* __restrict__ out) {
    constexpr int NROWS = ISNUM ? (N - 1) : (P - 1);
    const int t = threadIdx.x, wid = t >> 6, lane = t & 63;
    const float4 b1v = *(const float4*)&b1[lane * 4];
    const float* xg = xtg + grp * 1680;
    float b2r[6];
#pragma unroll
    for (int tt = 0; tt < 6; ++tt) b2r[tt] = b2[tt];
    const int bm = grp * 8 + (lane & 7);
    const int b_ = bm / MM, m = bm - b_ * MM;
    const int qe = (qc * 9 + 9 < 35) ? (qc * 9 + 9) : 35;
    for (int q = qc * 9 + wid; q < qe; q += 4) {
        int pivot, fix;
        if (ISNUM) { pivot = q / P; fix = q - pivot * P; }   // LOO over n cols, fixed row r
        else       { pivot = q / N; fix = q - pivot * N; }   // LOO over p rows, fixed col k
        float4 acc[8];
#pragma unroll
        for (int g = 0; g < 8; ++g) acc[g] = b1v;
        const float* wl = w1tb + lane * 4;
        for (int idx = 0; idx < NROWS; ++idx) {
            const int row = idx + (idx >= pivot);
            const int pos0 = ISNUM ? (fix * N + row) * 6 : (row * N + fix) * 6;
            const float* xp = xg + pos0 * 8;
#pragma unroll
            for (int tt = 0; tt < 6; ++tt) {
                const float4 xa = *(const float4*)(xp + tt * 8);
                const float4 xc = *(const float4*)(xp + tt * 8 + 4);
                const float4 w  = *(const float4*)wl; wl += DM;
                fma4(acc[0], w, xa.x); fma4(acc[1], w, xa.y);
                fma4(acc[2], w, xa.z); fma4(acc[3], w, xa.w);
                fma4(acc[4], w, xc.x); fma4(acc[5], w, xc.y);
                fma4(acc[6], w, xc.z); fma4(acc[7], w, xc.w);
            }
        }
#pragma unroll
        for (int g = 0; g < 8; ++g) {
            acc[g].x = fmaxf(acc[g].x, 0.f); acc[g].y = fmaxf(acc[g].y, 0.f);
            acc[g].z = fmaxf(acc[g].z, 0.f); acc[g].w = fmaxf(acc[g].w, 0.f);
        }
        const int c2 = q / 5, dd = q - c2 * 5;   // d0 = patch_seq[0] = 5 (ref hardcode)
#pragma unroll
        for (int h = 0; h < 2; ++h) {
            float yv0[8], yv1[8], yv2[8];
#pragma unroll
            for (int tt2 = 0; tt2 < 3; ++tt2) {
                const int tt = h * 3 + tt2;
                const float4 w2v = *(const float4*)&W2[tt * DM + lane * 4];
                float* yv = (tt2 == 0) ? yv0 : ((tt2 == 1) ? yv1 : yv2);
#pragma unroll
                for (int g = 0; g < 8; ++g)
                    yv[g] = acc[g].x * w2v.x + acc[g].y * w2v.y + acc[g].z * w2v.z + acc[g].w * w2v.w;
            }
            const float r0 = bfly8(yv0, lane);
            const float r1 = bfly8(yv1, lane);
            const float r2 = bfly8(yv2, lane);
            if (lane < 8) {
#pragma unroll
                for (int tt2 = 0; tt2 < 3; ++tt2) {
                    const int tt = h * 3 + tt2;
                    const int l = ISNUM ? (dd * 42 + c2 * 6 + tt) : (q * 6 + tt);
                    const float rv = (tt2 == 0) ? r0 : ((tt2 == 1) ? r1 : r2);
                    out[slab + b_ * MLT + l * MM + m] = rv + b2r[tt];
                }
            }
        }
    }
}

// ---------- everything-after-prep fused into one dispatch ----------
__global__ __launch_bounds__(256) void kfused(const float* __restrict__ xtg,
        const float* __restrict__ w1t, const float* __restrict__ recs,
        const float* __restrict__ b2s0, const float* __restrict__ b2s1, const float* __restrict__ b2s2,
        const float* __restrict__ nb1_0, const float* __restrict__ nW2_0, const float* __restrict__ nb2_0,
        const float* __restrict__ nb1_1, const float* __restrict__ nW2_1, const float* __restrict__ nb2_1,
        const float* __restrict__ nb1_2, const float* __restrict__ nW2_2, const float* __restrict__ nb2_2,
        const float* __restrict__ ss1b0, const float* __restrict__ ss2W0, const float* __restrict__ ss2b0,
        const float* __restrict__ ss1b1, const float* __restrict__ ss2W1, const float* __restrict__ ss2b1,
        const float* __restrict__ ns1b0, const float* __restrict__ ns2W0, const float* __restrict__ ns2b0,
        const float* __restrict__ ns1b1, const float* __restrict__ ns2W1, const float* __restrict__ ns2b1,
        float* __restrict__ out) {
    const int blk = blockIdx.x;
    if (blk < 1320) {
        if (blk < NBM)          ksize_body<2>(xtg, recs,        b2s0, blk,           0, out);
        else if (blk < 2 * NBM) ksize_body<4>(xtg, recs + 1024, b2s1, blk - NBM,     1, out);
        else                    ksize_body<6>(xtg, recs + 3072, b2s2, blk - 2 * NBM, 2, out);
    } else if (blk < 2145) {
        const int bn = blk - 1320;
        if (bn < 165) {
            int rel = bn;       knum_body<3, 70>(xtg, w1t,            nb1_0, nW2_0, nb2_0, rel / 3, rel % 3, 0, out);
        } else if (bn < 440) {
            int rel = bn - 165; knum_body<5, 42>(xtg, w1t + 69 * DM,  nb1_1, nW2_1, nb2_1, rel / 5, rel % 5, 1, out);
        } else {
            int rel = bn - 440; knum_body<7, 30>(xtg, w1t + 110 * DM, nb1_2, nW2_2, nb2_2, rel / 7, rel % 7, 2, out);
        }
    } else {
        const int bs = blk - 2145;                 // [0, 880)
        const int tc = bs / 220, rem = bs - tc * 220;
        const int grp = rem >> 2, qc = rem & 3;
        if (tc == 0)      kseq_body<0, 5, 7>(xtg, w1t + 139 * DM, ss1b0, ss2W0, ss2b0, grp, qc, 6 * BLM, out);
        else if (tc == 1) kseq_body<0, 7, 5>(xtg, w1t + 163 * DM, ss1b1, ss2W1, ss2b1, grp, qc, 7 * BLM, out);
        else if (tc == 2) kseq_body<1, 5, 7>(xtg, w1t + 199 * DM, ns1b0, ns2W0, ns2b0, grp, qc, 8 * BLM, out);
        else              kseq_body<1, 7, 5>(xtg, w1t + 235 * DM, ns1b1, ns2W1, ns2b1, grp, qc, 9 * BLM, out);
    }
}

extern "C" void kernel_launch(void* const* d_in, const int* in_sizes, int n_in,
                              void* d_out, int out_size, void* d_ws, size_t ws_size,
                              hipStream_t stream) {
    (void)in_sizes; (void)n_in; (void)out_size; (void)ws_size;
    const float* x = (const float*)d_in[0];
    const float *s1W[3], *s1b[3], *s2W[3], *s2b[3], *n1W[3], *n1b[3], *n2W[3], *n2b[3];
    for (int j = 0; j < 3; ++j) {
        int base = 1 + j * 8;
        s1W[j] = (const float*)d_in[base + 0]; s1b[j] = (const float*)d_in[base + 1];
        s2W[j] = (const float*)d_in[base + 2]; s2b[j] = (const float*)d_in[base + 3];
        n1W[j] = (const float*)d_in[base + 4]; n1b[j] = (const float*)d_in[base + 5];
        n2W[j] = (const float*)d_in[base + 6]; n2b[j] = (const float*)d_in[base + 7];
    }
    const float *ss1W[2], *ss1b[2], *ss2W[2], *ss2b[2], *ns1W[2], *ns1b[2], *ns2W[2], *ns2b[2];
    for (int j = 0; j < 2; ++j) {
        int base = 25 + j * 8;
        ss1W[j] = (const float*)d_in[base + 0]; ss1b[j] = (const float*)d_in[base + 1];
        ss2W[j] = (const float*)d_in[base + 2]; ss2b[j] = (const float*)d_in[base + 3];
        ns1W[j] = (const float*)d_in[base + 4]; ns1b[j] = (const float*)d_in[base + 5];
        ns2W[j] = (const float*)d_in[base + 6]; ns2b[j] = (const float*)d_in[base + 7];
    }
    float* out  = (float*)d_out;
    float* xtg  = (float*)d_ws + XTG_OFF;
    float* w1t  = (float*)d_ws + W1T_OFF;
    float* recs = (float*)d_ws + REC_OFF;

    knorm_trans<<<719, 256, 0, stream>>>(x,
        n1W[0], n1W[1], n1W[2],
        ss1W[0], ss1W[1], ns1W[0], ns1W[1],
        s1W[0], s1b[0], s2W[0],
        s1W[1], s1b[1], s2W[1],
        s1W[2], s1b[2], s2W[2],
        xtg, w1t, recs);
    kfused<<<3025, 256, 0, stream>>>(xtg, w1t, recs,
        s2b[0], s2b[1], s2b[2],
        n1b[0], n2W[0], n2b[0],
        n1b[1], n2W[1], n2b[1],
        n1b[2], n2W[2], n2b[2],
        ss1b[0], ss2W[0], ss2b[0],
        ss1b[1], ss2W[1], ss2b[1],
        ns1b[0], ns2W[0], ns2b[0],
        ns1b[1], ns2W[1], ns2b[1], out);
}